// Round 1
// baseline (433.546 us; speedup 1.0000x reference)
//
#include <hip/hip_runtime.h>
#include <hip/hip_bf16.h>

// Shapes (fixed by the reference):
//   B=256, S=512, H=1024, L=30
// Inputs (dict order):
//   0: x        [B,S,H] f32
//   1: entity_idx [B,4] i32
//   2: W_cls [H,H]  3: b_cls [H]
//   4: W_e1  [H,H]  5: b_e1  [H]
//   6: W_e2  [H,H]  7: b_e2  [H]
//   8: W_d1  [3H,H] 9: b_d1  [H]
//  10: W_d2  [H,H] 11: b_d2  [H]
//  12: W_out [H,L] 13: b_out [L]
// Output: [B,L] f32
//
// Algebra: layers after tanh are affine ->
//   out = [t0|t1|t2] @ Wfold + btot
//   Wfold[0:H]    = W_cls @ Wd1o[0:H]
//   Wfold[H:2H]   = W_e1  @ Wd1o[H:2H]
//   Wfold[2H:3H]  = W_e2  @ Wd1o[2H:3H]
//   Wd1o = W_d1 @ P1,  P1 = W_d2 @ W_out
//   btot = b_out + b_d2@W_out + b_d1@P1 + [b_cls|b_e1|b_e2]@Wd1o

#define B_ 256
#define S_ 512
#define H_ 1024
#define L_ 30

// ---------------------------------------------------------------------------
// Stage A: per-batch t0 = tanh(x[b,0,:]), t1 = tanh(mean span0), t2 = tanh(mean span1)
// grid (B, 2 column-halves, 2 roles), block 256. float2 per thread (512 cols/block).
// ---------------------------------------------------------------------------
__global__ __launch_bounds__(256) void span_tanh_kernel(
    const float* __restrict__ x, const int* __restrict__ eidx,
    float* __restrict__ T /* [B][3*H] */) {
  const int b = blockIdx.x;
  const int half = blockIdx.y;   // column half
  const int role = blockIdx.z;   // 0: x0 + sub span, 1: obj span
  const int t = threadIdx.x;
  const int col = half * 512 + t * 2;
  const float* xb = x + (size_t)b * S_ * H_;
  float* Tb = T + (size_t)b * (3 * H_);

  if (role == 0) {
    // x[b,0,:] -> tanh -> part 0
    float2 v0 = *(const float2*)(xb + col);
    float2 o0;
    o0.x = tanhf(v0.x);
    o0.y = tanhf(v0.y);
    *(float2*)(Tb + col) = o0;

    const int lo = eidx[b * 4 + 0], hi = eidx[b * 4 + 1];
    float ax = 0.f, ay = 0.f;
    for (int s = lo; s < hi; ++s) {
      float2 v = *(const float2*)(xb + (size_t)s * H_ + col);
      ax += v.x;
      ay += v.y;
    }
    const float inv = 1.0f / (float)max(hi - lo, 1);
    float2 o1;
    o1.x = tanhf(ax * inv);
    o1.y = tanhf(ay * inv);
    *(float2*)(Tb + H_ + col) = o1;
  } else {
    const int lo = eidx[b * 4 + 2], hi = eidx[b * 4 + 3];
    float ax = 0.f, ay = 0.f;
    for (int s = lo; s < hi; ++s) {
      float2 v = *(const float2*)(xb + (size_t)s * H_ + col);
      ax += v.x;
      ay += v.y;
    }
    const float inv = 1.0f / (float)max(hi - lo, 1);
    float2 o2;
    o2.x = tanhf(ax * inv);
    o2.y = tanhf(ay * inv);
    *(float2*)(Tb + 2 * H_ + col) = o2;
  }
}

// ---------------------------------------------------------------------------
// Fold GEMM: C[M][30] = A[M][1024] @ S[1024][30]   (f32)
// block 256 threads handles 32 rows; K staged in 128-chunks.
// ---------------------------------------------------------------------------
__global__ __launch_bounds__(256) void foldgemm_kernel(
    const float* __restrict__ A, const float* __restrict__ Smat,
    float* __restrict__ C) {
  const int K = H_;
  __shared__ float As[32][129];  // +1 pad: avoid same-bank across m
  __shared__ float Ss[128][30];
  const int m0 = blockIdx.x * 32;
  const int t = threadIdx.x;
  float acc[4] = {0.f, 0.f, 0.f, 0.f};

  for (int kc = 0; kc < K; kc += 128) {
#pragma unroll
    for (int i = 0; i < 16; ++i) {
      int idx = t + i * 256;
      int r = idx >> 7, c = idx & 127;
      As[r][c] = A[(size_t)(m0 + r) * K + kc + c];
    }
#pragma unroll
    for (int i = 0; i < 15; ++i) {
      int idx = t + i * 256;  // < 3840
      int r = idx / 30, c = idx - r * 30;
      Ss[r][c] = Smat[(size_t)(kc + r) * L_ + c];
    }
    __syncthreads();
#pragma unroll
    for (int pi = 0; pi < 4; ++pi) {
      int p = t + pi * 256;
      if (p < 960) {
        int m = p / 30, n = p - m * 30;
        float s = 0.f;
#pragma unroll 8
        for (int k = 0; k < 128; ++k) s += As[m][k] * Ss[k][n];
        acc[pi] += s;
      }
    }
    __syncthreads();
  }
#pragma unroll
  for (int pi = 0; pi < 4; ++pi) {
    int p = t + pi * 256;
    if (p < 960) {
      int m = p / 30, n = p - m * 30;
      C[(size_t)(m0 + m) * L_ + n] = acc[pi];
    }
  }
}

// ---------------------------------------------------------------------------
// btot[n] = b_out[n] + sum_k b_d2[k]W_out[k,n] + b_d1[k]P1[k,n]
//          + b_cls[k]Wd1o[k,n] + b_e1[k]Wd1o[H+k,n] + b_e2[k]Wd1o[2H+k,n]
// grid 30, block 256
// ---------------------------------------------------------------------------
__global__ __launch_bounds__(256) void bias_kernel(
    const float* __restrict__ b_out, const float* __restrict__ b_d2,
    const float* __restrict__ W_out, const float* __restrict__ b_d1,
    const float* __restrict__ P1, const float* __restrict__ b_cls,
    const float* __restrict__ b_e1, const float* __restrict__ b_e2,
    const float* __restrict__ Wd1o, float* __restrict__ btot) {
  const int n = blockIdx.x;
  const int t = threadIdx.x;
  __shared__ float red[256];
  float s = 0.f;
  for (int k = t; k < H_; k += 256) {
    s += b_d2[k] * W_out[(size_t)k * L_ + n];
    s += b_d1[k] * P1[(size_t)k * L_ + n];
    s += b_cls[k] * Wd1o[(size_t)k * L_ + n];
    s += b_e1[k] * Wd1o[(size_t)(H_ + k) * L_ + n];
    s += b_e2[k] * Wd1o[(size_t)(2 * H_ + k) * L_ + n];
  }
  red[t] = s;
  __syncthreads();
  for (int off = 128; off > 0; off >>= 1) {
    if (t < off) red[t] += red[t + off];
    __syncthreads();
  }
  if (t == 0) btot[n] = red[0] + b_out[n];
}

// ---------------------------------------------------------------------------
// Final: out[b][n] = sum_k T[b][k] * Wfold[k][n] + btot[n]
// grid B, block 256. T row staged in LDS; 8 k-slices x 30 n.
// ---------------------------------------------------------------------------
__global__ __launch_bounds__(256) void final_kernel(
    const float* __restrict__ T, const float* __restrict__ Wf,
    const float* __restrict__ btot, float* __restrict__ out) {
  __shared__ float Ts[3 * H_];
  __shared__ float red[8][30];
  const int b = blockIdx.x;
  const int t = threadIdx.x;
#pragma unroll
  for (int i = 0; i < 12; ++i) Ts[t + i * 256] = T[(size_t)b * (3 * H_) + t + i * 256];
  __syncthreads();
  if (t < 240) {
    const int n = t % 30, p = t / 30;
    float s = 0.f;
    const int k0 = p * 384;
#pragma unroll 4
    for (int k = k0; k < k0 + 384; ++k) s += Ts[k] * Wf[(size_t)k * L_ + n];
    red[p][n] = s;
  }
  __syncthreads();
  if (t < L_) {
    float s = btot[t];
#pragma unroll
    for (int p = 0; p < 8; ++p) s += red[p][t];
    out[(size_t)b * L_ + t] = s;
  }
}

extern "C" void kernel_launch(void* const* d_in, const int* in_sizes, int n_in,
                              void* d_out, int out_size, void* d_ws, size_t ws_size,
                              hipStream_t stream) {
  const float* x = (const float*)d_in[0];
  const int* eidx = (const int*)d_in[1];
  const float* W_cls = (const float*)d_in[2];
  const float* b_cls = (const float*)d_in[3];
  const float* W_e1 = (const float*)d_in[4];
  const float* b_e1 = (const float*)d_in[5];
  const float* W_e2 = (const float*)d_in[6];
  const float* b_e2 = (const float*)d_in[7];
  const float* W_d1 = (const float*)d_in[8];
  const float* b_d1 = (const float*)d_in[9];
  const float* W_d2 = (const float*)d_in[10];
  const float* b_d2 = (const float*)d_in[11];
  const float* W_out = (const float*)d_in[12];
  const float* b_out = (const float*)d_in[13];
  float* out = (float*)d_out;

  // Workspace layout (f32)
  float* ws = (float*)d_ws;
  float* T = ws;                       // 256*3072 = 786432
  float* P1 = T + 786432;              // 1024*30  = 30720
  float* Wd1o = P1 + 30720;            // 3072*30  = 92160
  float* Wfold = Wd1o + 92160;         // 3072*30  = 92160
  float* btot = Wfold + 92160;         // 32
  // total ~1.0M floats ~4.0 MB

  // Stage A (independent of folds)
  span_tanh_kernel<<<dim3(B_, 2, 2), 256, 0, stream>>>(x, eidx, T);

  // Fold chain
  foldgemm_kernel<<<H_ / 32, 256, 0, stream>>>(W_d2, W_out, P1);          // P1 = W_d2@W_out
  foldgemm_kernel<<<3 * H_ / 32, 256, 0, stream>>>(W_d1, P1, Wd1o);       // Wd1o = W_d1@P1
  foldgemm_kernel<<<H_ / 32, 256, 0, stream>>>(W_cls, Wd1o, Wfold);
  foldgemm_kernel<<<H_ / 32, 256, 0, stream>>>(W_e1, Wd1o + (size_t)H_ * L_, Wfold + (size_t)H_ * L_);
  foldgemm_kernel<<<H_ / 32, 256, 0, stream>>>(W_e2, Wd1o + (size_t)2 * H_ * L_, Wfold + (size_t)2 * H_ * L_);

  bias_kernel<<<L_, 256, 0, stream>>>(b_out, b_d2, W_out, b_d1, P1,
                                      b_cls, b_e1, b_e2, Wd1o, btot);

  final_kernel<<<B_, 256, 0, stream>>>(T, Wfold, btot, out);
}

// Round 2
// 167.636 us; speedup vs baseline: 2.5862x; 2.5862x over previous
//
#include <hip/hip_runtime.h>
#include <hip/hip_bf16.h>

// B=256, S=512, H=1024, L=30
// out = [tanh(x0)|tanh(mean_sub)|tanh(mean_obj)] @ Wfold + btot
//   P1 = W_d2@W_out; Wd1o = W_d1@P1; Wfold[z] = W_z@Wd1o[z]
//   btot = b_out + b_d2@W_out + b_d1@P1 + [b_cls|b_e1|b_e2]@Wd1o

#define B_ 256
#define S_ 512
#define H_ 1024
#define L_ 30
#define NCHUNK 8      // 512/64 rows per chunk
#define KSPLIT 8      // K=1024 -> 8 chunks of 128

// ---------------------------------------------------------------------------
// Span partial sums: grid (B, NCHUNK, 2), block 256 (float4/lane = full row).
// Block sums rows [chunk*64, chunk*64+64) ∩ [lo,hi) -> Pspan[b][role][chunk][H].
// Blocks with empty intersection exit without writing (final kernel knows which
// chunks overlap from eidx).
// ---------------------------------------------------------------------------
__global__ __launch_bounds__(256) void span_partial_kernel(
    const float* __restrict__ x, const int* __restrict__ eidx,
    float* __restrict__ Pspan) {
  const int b = blockIdx.x;
  const int chunk = blockIdx.y;
  const int role = blockIdx.z;
  const int lo = eidx[b * 4 + 2 * role];
  const int hi = eidx[b * 4 + 2 * role + 1];
  int s0 = max(lo, chunk * 64);
  int s1 = min(hi, chunk * 64 + 64);
  if (s0 >= s1) return;

  const int col = threadIdx.x * 4;
  const float* base = x + (size_t)b * S_ * H_ + col;
  float ax0 = 0.f, ay0 = 0.f, az0 = 0.f, aw0 = 0.f;
  float ax1 = 0.f, ay1 = 0.f, az1 = 0.f, aw1 = 0.f;
  int s = s0;
  for (; s + 2 <= s1; s += 2) {
    float4 v0 = *(const float4*)(base + (size_t)s * H_);
    float4 v1 = *(const float4*)(base + (size_t)(s + 1) * H_);
    ax0 += v0.x; ay0 += v0.y; az0 += v0.z; aw0 += v0.w;
    ax1 += v1.x; ay1 += v1.y; az1 += v1.z; aw1 += v1.w;
  }
  if (s < s1) {
    float4 v0 = *(const float4*)(base + (size_t)s * H_);
    ax0 += v0.x; ay0 += v0.y; az0 += v0.z; aw0 += v0.w;
  }
  float4 o;
  o.x = ax0 + ax1; o.y = ay0 + ay1; o.z = az0 + az1; o.w = aw0 + aw1;
  *(float4*)(Pspan + (((size_t)b * 2 + role) * NCHUNK + chunk) * H_ + col) = o;
}

// ---------------------------------------------------------------------------
// Fold GEMM partial: Cp[ks][M][30] = A[rows, k-chunk] @ S[k-chunk][30]
// block = 64 threads (1 wave), thread owns one row, acc[30] in VGPRs.
// A staged in LDS (padded, ds_read_b128); S read at wave-uniform addresses
// (-> scalar loads; FMA uses SGPR operand).
// ---------------------------------------------------------------------------
__device__ __forceinline__ void foldgemm_body(
    const float* __restrict__ A, const float* __restrict__ Smat,
    float* __restrict__ Cp, int M, int rowblk, int ks, int out_row_off) {
  __shared__ float As[64][132];  // 132*4B = 528 = 33*16 -> b128-aligned rows
  const int t = threadIdx.x;
  const int k0 = ks * 128;

#pragma unroll
  for (int i = 0; i < 32; ++i) {
    int idx = t + i * 64;           // float4 units, 0..2047
    int r = idx >> 5;               // 32 float4 per row
    int c = (idx & 31) << 2;
    float4 v = *(const float4*)(A + (size_t)(rowblk + r) * H_ + k0 + c);
    *(float4*)&As[r][c] = v;
  }
  __syncthreads();

  float acc[30];
#pragma unroll
  for (int n = 0; n < 30; ++n) acc[n] = 0.f;

  for (int kk = 0; kk < 128; kk += 4) {
    float4 a = *(const float4*)&As[t][kk];
    const float* Sr = Smat + (size_t)(k0 + kk) * 30;
#pragma unroll
    for (int n = 0; n < 30; ++n) {
      acc[n] += a.x * Sr[n] + a.y * Sr[n + 30] + a.z * Sr[n + 60] + a.w * Sr[n + 90];
    }
  }

  float* Crow = Cp + ((size_t)ks * M + out_row_off + rowblk + t) * 30;
#pragma unroll
  for (int n = 0; n < 30; ++n) Crow[n] = acc[n];
}

__global__ __launch_bounds__(64) void foldgemm_single(
    const float* __restrict__ A, const float* __restrict__ Smat,
    float* __restrict__ Cp, int M) {
  foldgemm_body(A, Smat, Cp, M, blockIdx.x * 64, blockIdx.y, 0);
}

// Three independent folds in one launch: z picks (A_z, Wd1o slice, out slice)
__global__ __launch_bounds__(64) void foldgemm_tri(
    const float* __restrict__ A0, const float* __restrict__ A1,
    const float* __restrict__ A2, const float* __restrict__ Wd1o,
    float* __restrict__ Cp) {
  const int z = blockIdx.z;
  const float* A = (z == 0) ? A0 : ((z == 1) ? A1 : A2);
  const float* Smat = Wd1o + (size_t)z * H_ * 30;
  foldgemm_body(A, Smat, Cp, 3 * H_, blockIdx.x * 64, blockIdx.y, z * H_);
}

// C[i] = sum_ks Cp[ks][i]
__global__ __launch_bounds__(256) void reduce8_kernel(
    const float* __restrict__ Cp, float* __restrict__ C, int N) {
  int i = blockIdx.x * 256 + threadIdx.x;
  if (i >= N) return;
  float s = 0.f;
#pragma unroll
  for (int ks = 0; ks < KSPLIT; ++ks) s += Cp[(size_t)ks * N + i];
  C[i] = s;
}

// ---------------------------------------------------------------------------
// btot[n] (grid 30, block 256)
// ---------------------------------------------------------------------------
__global__ __launch_bounds__(256) void bias_kernel(
    const float* __restrict__ b_out, const float* __restrict__ b_d2,
    const float* __restrict__ W_out, const float* __restrict__ b_d1,
    const float* __restrict__ P1, const float* __restrict__ b_cls,
    const float* __restrict__ b_e1, const float* __restrict__ b_e2,
    const float* __restrict__ Wd1o, float* __restrict__ btot) {
  const int n = blockIdx.x;
  const int t = threadIdx.x;
  __shared__ float red[256];
  float s = 0.f;
  for (int k = t; k < H_; k += 256) {
    s += b_d2[k] * W_out[(size_t)k * L_ + n];
    s += b_d1[k] * P1[(size_t)k * L_ + n];
    s += b_cls[k] * Wd1o[(size_t)k * L_ + n];
    s += b_e1[k] * Wd1o[(size_t)(H_ + k) * L_ + n];
    s += b_e2[k] * Wd1o[(size_t)(2 * H_ + k) * L_ + n];
  }
  red[t] = s;
  __syncthreads();
  for (int off = 128; off > 0; off >>= 1) {
    if (t < off) red[t] += red[t + off];
    __syncthreads();
  }
  if (t == 0) btot[n] = red[0] + b_out[n];
}

// ---------------------------------------------------------------------------
// Final: build T[b] (tanh(x0), tanh(span means from partials)) in LDS, then
// out[b][n] = T[b] . Wfold[:,n] + btot[n].  grid B, block 256.
// ---------------------------------------------------------------------------
__global__ __launch_bounds__(256) void final_kernel(
    const float* __restrict__ x, const int* __restrict__ eidx,
    const float* __restrict__ Pspan, const float* __restrict__ Wf,
    const float* __restrict__ btot, float* __restrict__ out) {
  __shared__ float Ts[3 * H_];
  __shared__ float red[8][30];
  const int b = blockIdx.x;
  const int t = threadIdx.x;
  const int col = t * 4;

  // part 0: tanh(x[b,0,:])
  {
    float4 v = *(const float4*)(x + (size_t)b * S_ * H_ + col);
    Ts[col + 0] = tanhf(v.x);
    Ts[col + 1] = tanhf(v.y);
    Ts[col + 2] = tanhf(v.z);
    Ts[col + 3] = tanhf(v.w);
  }
  // parts 1,2: span means
#pragma unroll
  for (int role = 0; role < 2; ++role) {
    const int lo = eidx[b * 4 + 2 * role];
    const int hi = eidx[b * 4 + 2 * role + 1];
    const int c0 = lo >> 6;
    const int c1 = (hi - 1) >> 6;
    float ax = 0.f, ay = 0.f, az = 0.f, aw = 0.f;
    for (int c = c0; c <= c1; ++c) {
      float4 v = *(const float4*)(Pspan + (((size_t)b * 2 + role) * NCHUNK + c) * H_ + col);
      ax += v.x; ay += v.y; az += v.z; aw += v.w;
    }
    const float inv = 1.0f / (float)(hi - lo);
    float* Td = Ts + (1 + role) * H_ + col;
    Td[0] = tanhf(ax * inv);
    Td[1] = tanhf(ay * inv);
    Td[2] = tanhf(az * inv);
    Td[3] = tanhf(aw * inv);
  }
  __syncthreads();

  if (t < 240) {
    const int n = t % 30, p = t / 30;
    const int k0 = p * 384;
    float s = 0.f;
#pragma unroll 4
    for (int k = k0; k < k0 + 384; ++k) s += Ts[k] * Wf[(size_t)k * L_ + n];
    red[p][n] = s;
  }
  __syncthreads();
  if (t < L_) {
    float s = btot[t];
#pragma unroll
    for (int p = 0; p < 8; ++p) s += red[p][t];
    out[(size_t)b * L_ + t] = s;
  }
}

extern "C" void kernel_launch(void* const* d_in, const int* in_sizes, int n_in,
                              void* d_out, int out_size, void* d_ws, size_t ws_size,
                              hipStream_t stream) {
  const float* x = (const float*)d_in[0];
  const int* eidx = (const int*)d_in[1];
  const float* W_cls = (const float*)d_in[2];
  const float* b_cls = (const float*)d_in[3];
  const float* W_e1 = (const float*)d_in[4];
  const float* b_e1 = (const float*)d_in[5];
  const float* W_e2 = (const float*)d_in[6];
  const float* b_e2 = (const float*)d_in[7];
  const float* W_d1 = (const float*)d_in[8];
  const float* b_d1 = (const float*)d_in[9];
  const float* W_d2 = (const float*)d_in[10];
  const float* b_d2 = (const float*)d_in[11];
  const float* W_out = (const float*)d_in[12];
  const float* b_out = (const float*)d_in[13];
  float* out = (float*)d_out;

  float* ws = (float*)d_ws;
  float* Pspan = ws;                    // 256*2*8*1024 = 4,194,304
  float* P1p   = Pspan + 4194304;       // 8*1024*30   =   245,760
  float* P1    = P1p + 245760;          // 1024*30     =    30,720
  float* Wp    = P1 + 30720;            // 8*3072*30   =   737,280
  float* Wd1o  = Wp + 737280;           // 3072*30     =    92,160
  float* Wp2   = Wd1o + 92160;          // 8*3072*30   =   737,280
  float* Wfold = Wp2 + 737280;          // 3072*30     =    92,160
  float* btot  = Wfold + 92160;         // 32

  // Span partials (big HBM read) first.
  span_partial_kernel<<<dim3(B_, NCHUNK, 2), 256, 0, stream>>>(x, eidx, Pspan);

  // Fold chain (small, VALU-bound, scalar-operand GEMMs).
  foldgemm_single<<<dim3(H_ / 64, KSPLIT), 64, 0, stream>>>(W_d2, W_out, P1p, H_);
  reduce8_kernel<<<(H_ * 30 + 255) / 256, 256, 0, stream>>>(P1p, P1, H_ * 30);

  foldgemm_single<<<dim3(3 * H_ / 64, KSPLIT), 64, 0, stream>>>(W_d1, P1, Wp, 3 * H_);
  reduce8_kernel<<<(3 * H_ * 30 + 255) / 256, 256, 0, stream>>>(Wp, Wd1o, 3 * H_ * 30);

  foldgemm_tri<<<dim3(H_ / 64, KSPLIT, 3), 64, 0, stream>>>(W_cls, W_e1, W_e2, Wd1o, Wp2);
  reduce8_kernel<<<(3 * H_ * 30 + 255) / 256, 256, 0, stream>>>(Wp2, Wfold, 3 * H_ * 30);

  bias_kernel<<<L_, 256, 0, stream>>>(b_out, b_d2, W_out, b_d1, P1,
                                      b_cls, b_e1, b_e2, Wd1o, btot);

  final_kernel<<<B_, 256, 0, stream>>>(x, eidx, Pspan, Wfold, btot, out);
}